// Round 6
// baseline (249.362 us; speedup 1.0000x reference)
//
#include <hip/hip_runtime.h>
#include <hip/hip_cooperative_groups.h>

namespace cg = cooperative_groups;

// ---------------------------------------------------------------------------
// TaskAlignedAssigner (YOLO TAL) for MI355X — single cooperative kernel.
// B=32, A=8400, M=32, C=80 (derived at runtime; M<=32 so a gt-column mask
// fits one uint32 per anchor; C%4==0 assumed for float4 ts writes).
//
// Outputs (concatenated float32, return order):
//   tl (B,A) | tb (B,A,4) | ts (B,A,C) | fg (B,A) | tgt (B,A)
//
// R1: removed global atomic histogram (65us same-cacheline serialization).
// R2: fix2 wave-parallel register scan (was 71.7us dependent-latency).
// R3 (regressed): select1 inside 32-block fix2 -> 32/256 CUs busy.
// R4: select1 full-grid again; 5 kernels + memset = 74.5us. Per-kernel work
//     sums to ~30us; the rest is 6 serialized dispatch boundaries.
// R5: ONE cooperative kernel, 4 phases, 3 grid.sync(). Phase bodies are the
//     proven R4 kernels as grid-stride task loops. Removes ~5 dispatch
//     boundaries; cnt zeroed in-kernel; fix1 applied via per-task pair list
//     (single-writer per anchor) so P1 can plain-store rowbits.
// ---------------------------------------------------------------------------

#define EPS_IN   1e-9f
#define IOU_EPS  1e-7f

__device__ __forceinline__ float iou_pair(const float4 p, const float4 g) {
#pragma clang fp contract(off)
    float w1 = p.z - p.x;
    float h1 = (p.w - p.y) + IOU_EPS;
    float w2 = g.z - g.x;
    float h2 = (g.w - g.y) + IOU_EPS;
    float iw = fminf(p.z, g.z) - fmaxf(p.x, g.x);
    iw = fmaxf(iw, 0.0f);
    float ih = fminf(p.w, g.w) - fmaxf(p.y, g.y);
    ih = fmaxf(ih, 0.0f);
    float inter = iw * ih;
    float uni = w1 * h1 + w2 * h2 - inter + IOU_EPS;
    float r = inter / uni;
    return fmaxf(r, 0.0f);
}

// mask_gt dtype detection (int32 / f32 / u8), wave-uniform. mask[b][0] is
// always true (n_gt>=1) so each dtype is observable in the first nw words.
__device__ __forceinline__ int detect_mode(const void* mg, int nw) {
    const unsigned* w = (const unsigned*)mg;
    int lane = threadIdx.x & 63;
    int badI = 0, badF = 0;
    for (int i = lane; i < nw; i += 64) {
        unsigned v = w[i];
        badI |= (v > 1u);
        badF |= (v != 0u && v != 0x3F800000u);
    }
    unsigned long long bI = __ballot(badI != 0);
    unsigned long long bF = __ballot(badF != 0);
    return bI ? (bF ? 2 : 1) : 0;
}

__device__ __forceinline__ bool mask_at(const void* mg, int mode, int idx) {
    if (mode == 0) return ((const int*)mg)[idx] != 0;
    if (mode == 1) return ((const float*)mg)[idx] != 0.0f;
    return ((const unsigned char*)mg)[idx] != 0;
}

__global__ __launch_bounds__(256, 2) void k_tal(
        const float* __restrict__ pds, const float4* __restrict__ pdb,
        const float2* __restrict__ anc, const int* __restrict__ gtl,
        const float4* __restrict__ gtb, const void* mg,
        float* __restrict__ out,
        unsigned* __restrict__ rowbits, int* __restrict__ tgtfg,
        unsigned long long* __restrict__ colKey, int* __restrict__ cnt,
        unsigned char* __restrict__ needByte,
        int A, int B, int M, int C, int nCh, int nw) {
    cg::grid_group grid = cg::this_grid();
    int tid = threadIdx.x;
    int lane = tid & 63, wid = tid >> 6;
    int mode = detect_mode(mg, nw);

    __shared__ float4 sg[32];
    __shared__ unsigned char smg[32];
    __shared__ unsigned long long skey[4];
    __shared__ int sin_[4];
    __shared__ int fixA[32];
    __shared__ unsigned char fixG[32];
    __shared__ int sL;
    __shared__ int shist[32];
    __shared__ float snorm[256];
    __shared__ int stl[256];

    int nBlk = gridDim.x;
    int colTasks = B * M;
    int anchTasks = nCh * B;

    // ---- P1: columns (colKey + needByte, inline hasin) & anchors (rowbits) ----
    if (blockIdx.x == 0) {           // zero the fg-count histogram for P2
        for (int i = tid; i < B * M; i += 256) cnt[i] = 0;
    }
    for (int task = blockIdx.x; task < colTasks + anchTasks; task += nBlk) {
        if (task < colTasks) {
            int b = task / M, m = task - b * M;
            if (mask_at(mg, mode, b * M + m)) {
                float4 g4 = gtb[b * M + m];
                size_t bA = (size_t)b * A;
                unsigned long long key = 0ull;
                int hasin = 0;
                for (int a = tid; a < A; a += 256) {
                    float v = iou_pair(pdb[bA + a], g4);
                    unsigned long long k =
                        ((unsigned long long)__float_as_uint(v) << 32) |
                        (0xFFFFFFFFu - (unsigned)a);
                    if (k > key) key = k;
                    float2 an = anc[a];
                    float mn = fminf(fminf(an.x - g4.x, an.y - g4.y),
                                     fminf(g4.z - an.x, g4.w - an.y));
                    hasin |= (mn > EPS_IN);
                }
                for (int off = 32; off; off >>= 1) {
                    unsigned long long o = __shfl_down(key, off);
                    if (o > key) key = o;
                    hasin |= __shfl_down(hasin, off);
                }
                if (lane == 0) { skey[wid] = key; sin_[wid] = hasin; }
                __syncthreads();
                if (tid == 0) {
                    for (int i = 1; i < 4; i++) { if (skey[i] > key) key = skey[i]; hasin |= sin_[i]; }
                    colKey[b * M + m] = key;
                    needByte[b * M + m] = hasin ? 0 : 1;   // fix1 need flag
                }
            }
            __syncthreads();
        } else {
            int c = task - colTasks;
            int b = c / nCh, ch = c - b * nCh;
            int a = ch * 256 + tid;
            if (tid < M) {
                sg[tid]  = gtb[b * M + tid];
                smg[tid] = mask_at(mg, mode, b * M + tid) ? 1 : 0;
            }
            __syncthreads();
            if (a < A) {
                float2 an = anc[a];
                unsigned bits = 0u;
                for (int m = 0; m < M; m++) {
                    float4 g = sg[m];
                    float mn = fminf(fminf(an.x - g.x, an.y - g.y),
                                     fminf(g.z - an.x, g.w - an.y));
                    if (mn > EPS_IN && smg[m]) bits |= (1u << m);
                }
                rowbits[(size_t)b * A + a] = bits;      // plain store (sole writer in P1)
            }
            __syncthreads();
        }
    }
    grid.sync();

    // ---- P2: select1 + fix1 merge + histogram ----
    for (int task = blockIdx.x; task < anchTasks; task += nBlk) {
        int b = task / nCh, ch = task - b * nCh;
        int a = ch * 256 + tid;
        if (tid < M) sg[tid] = gtb[b * M + tid];
        if (tid < 64) {
            bool needv = false; int best = -1;
            if (tid < M && mask_at(mg, mode, b * M + tid) && needByte[b * M + tid])
                needv = true;
            unsigned nb = (unsigned)__ballot(needv);
            if (needv) {
                unsigned long long key = colKey[b * M + tid];
                best = (int)(0xFFFFFFFFu - (unsigned)(key & 0xFFFFFFFFull));
                int pos = __popc(nb & ((1u << tid) - 1u));
                fixA[pos] = best; fixG[pos] = (unsigned char)tid;
            }
            if (tid == 0) sL = __popc(nb);
        }
        if (tid < 32) shist[tid] = 0;
        __syncthreads();
        if (a < A) {
            size_t idx = (size_t)b * A + a;
            unsigned bits = rowbits[idx];
            unsigned add = 0u;
            int L = sL;
            for (int j = 0; j < L; j++) if (fixA[j] == a) add |= (1u << fixG[j]);
            if (add) { atomicOr(&rowbits[idx], add); bits |= add; }  // single writer per anchor
            int pc = __popc(bits);
            int t;
            if (pc > 1) {
                float4 p = pdb[idx];
                float bv = -1.0f; int bm = 0;
                for (int m = 0; m < M; m++) {
                    float v = iou_pair(p, sg[m]);
                    if (v > bv) { bv = v; bm = m; }
                }
                t = bm;
            } else if (pc == 1) t = __ffs(bits) - 1;
            else t = -1;
            tgtfg[idx] = t;
            if (t >= 0) atomicAdd(&shist[t], 1);
        }
        __syncthreads();
        if (tid < 32 && shist[tid]) atomicAdd(&cnt[b * M + tid], shist[tid]);
        __syncthreads();
    }
    grid.sync();

    // ---- P3: fix2 order-dependent scan, wave 0 of first B blocks ----
    if (blockIdx.x < B && tid < 64) {
        int b = blockIdx.x;
        bool mv = false; int best = -1;
        if (tid < M) mv = mask_at(mg, mode, b * M + tid);
        if (mv) {
            unsigned long long key = colKey[b * M + tid];
            best = (int)(0xFFFFFFFFu - (unsigned)(key & 0xFFFFFFFFull));
        }
        unsigned maskbits = (unsigned)__ballot(mv);
        int myBest = (tid < 32) ? best : -1;
        int myCnt  = (tid < 32 && tid < M) ? cnt[b * M + tid] : 0;
        int myPre  = (myBest >= 0) ? tgtfg[(size_t)b * A + myBest] : -1;
        unsigned myEq = 0u;
        for (int g2 = 0; g2 < 32; g2++) {
            int bb = __shfl(myBest, g2);
            if (bb == myBest) myEq |= (1u << g2);
        }
        unsigned applied = 0u;
        for (int g = 0; g < M; g++) {
            int cg_ = __shfl(myCnt, g);
            if (((maskbits >> g) & 1u) && cg_ == 0) {
                int a       = __shfl(myBest, g);
                unsigned em = __shfl(myEq, g);
                unsigned x  = applied & em;
                int old;
                if (x) old = 31 - __clz(x);      // last earlier step that took this anchor
                else   old = __shfl(myPre, g);   // select1's owner (-1 = background)
                if (tid == old) myCnt--;
                if (tid == g)   myCnt++;
                applied |= (1u << g);
                if (tid == 0)
                    atomicOr(&rowbits[(size_t)b * A + a], 1u << g);  // fire-and-forget
            }
        }
    }
    grid.sync();

    // ---- P4: final select + all outputs (fused ts) ----
    size_t BA = (size_t)B * A;
    for (int task = blockIdx.x; task < anchTasks; task += nBlk) {
        int b = task / nCh, ch = task - b * nCh;
        int base = ch * 256;
        int a = base + tid;
        if (tid < M) { sg[tid] = gtb[b * M + tid]; stl[tid] = gtl[b * M + tid]; }
        __syncthreads();
        int labv = (tid < M) ? stl[tid] : 0;   // keep gtl in regs via sg-stage trick
        __syncthreads();
        if (tid < M) shist[tid] = labv;        // shist reused as label store
        __syncthreads();
        if (a < A) {
            size_t idx = (size_t)b * A + a;
            unsigned bits = rowbits[idx];
            int pc = __popc(bits);
            int tgt, fg; float ov = 0.0f;
            float4 p = pdb[idx];
            if (pc > 1) {
                float bv = -1.0f; int bm = 0;
                for (int m = 0; m < M; m++) {
                    float v = iou_pair(p, sg[m]);
                    if (v > bv) { bv = v; bm = m; }
                }
                tgt = bm; fg = 1; ov = bv;
            } else if (pc == 1) {
                tgt = __ffs(bits) - 1; fg = 1;
                ov = iou_pair(p, sg[tgt]);
            } else { tgt = 0; fg = 0; }
            int lab = shist[tgt];
            int tl = min(max(lab, 0), C);            // clip(., 0, NUM_CLASSES)
            float norm = 0.0f;
            if (fg) {
                int li = (lab >= 0 && lab < C) ? lab : 0;
                float cls = pds[idx * (size_t)C + li];
                float ov6 = powf(ov, 6.0f);          // overlaps ** BETA
                float v = cls * ov6;                 // align_metric at (a, tgt)
                norm = v * ov / (v + 1e-9f);         // pam*pov/(pam+eps)
            }
            out[idx] = (float)tl;                                // tl
            ((float4*)(out + BA))[idx] = sg[tgt];                // tb
            out[BA * (size_t)(5 + C) + idx] = fg ? 1.0f : 0.0f;  // fg
            out[BA * (size_t)(6 + C) + idx] = (float)tgt;        // tgt
            snorm[tid] = norm;
            stl[tid] = tl;
        }
        __syncthreads();
        int cntA = min(256, A - base);
        int rowf4 = C >> 2;
        int nf4 = cntA * rowf4;
        float4* tsb = (float4*)(out + BA * 5 + ((size_t)b * A + base) * C);
        int q = 256 / rowf4, r = 256 - q * rowf4;
        int row = tid / rowf4;
        int c4  = tid - row * rowf4;
        for (int i = tid; i < nf4; i += 256) {
            float nv = snorm[row];
            int tl   = stl[row];
            int cb = c4 * 4;
            float4 v;
            v.x = (tl == cb + 0) ? nv : 0.0f;
            v.y = (tl == cb + 1) ? nv : 0.0f;
            v.z = (tl == cb + 2) ? nv : 0.0f;
            v.w = (tl == cb + 3) ? nv : 0.0f;
            tsb[i] = v;
            row += q; c4 += r;
            if (c4 >= rowf4) { c4 -= rowf4; row++; }
        }
        __syncthreads();
    }
}

extern "C" void kernel_launch(void* const* d_in, const int* in_sizes, int n_in,
                              void* d_out, int out_size, void* d_ws, size_t ws_size,
                              hipStream_t stream) {
    const float*  pd_scores = (const float*)d_in[0];
    const float4* pd_bboxes = (const float4*)d_in[1];
    const float2* anc       = (const float2*)d_in[2];
    const int*    gt_labels = (const int*)d_in[3];
    const float4* gt_bboxes = (const float4*)d_in[4];
    const void*   mask_gt   = d_in[5];

    int A = in_sizes[2] / 2;
    int B = in_sizes[1] / (A * 4);
    int M = in_sizes[3] / B;
    int C = (int)((long long)in_sizes[0] / ((long long)B * A));
    int nCh = (A + 255) / 256;
    int nw = (B * M) / 4; if (nw > 256) nw = 256;

    char* wp = (char*)d_ws;
    auto carve = [&](size_t bytes) -> char* {
        char* r = wp; wp += (bytes + 255) & ~(size_t)255; return r;
    };
    unsigned* rowbits          = (unsigned*)carve((size_t)B * A * 4);
    int* tgtfg                 = (int*)carve((size_t)B * A * 4);
    unsigned long long* colKey = (unsigned long long*)carve((size_t)B * M * 8);
    int* cnt                   = (int*)carve((size_t)B * M * 4);
    unsigned char* needByte    = (unsigned char*)carve((size_t)B * M);

    float* out = (float*)d_out;

    void* args[] = {
        (void*)&pd_scores, (void*)&pd_bboxes, (void*)&anc, (void*)&gt_labels,
        (void*)&gt_bboxes, (void*)&mask_gt, (void*)&out,
        (void*)&rowbits, (void*)&tgtfg, (void*)&colKey, (void*)&cnt,
        (void*)&needByte,
        (void*)&A, (void*)&B, (void*)&M, (void*)&C, (void*)&nCh, (void*)&nw
    };
    // 512 blocks x 256 thr: __launch_bounds__(256,2) guarantees 2 blocks/CU
    // co-residency on 256 CUs -> cooperative launch always fits.
    hipLaunchCooperativeKernel((void*)k_tal, dim3(512), dim3(256), args, 0, stream);
}

// Round 7
// 127.472 us; speedup vs baseline: 1.9562x; 1.9562x over previous
//
#include <hip/hip_runtime.h>

// ---------------------------------------------------------------------------
// TaskAlignedAssigner (YOLO TAL) for MI355X — 3 dispatches, no grid.sync.
// B=32, A=8400, M=32, C=80 (derived at runtime; M<=32 so a gt-column mask
// fits one uint32 per anchor; C%4==0 assumed for float4 ts writes).
//
// Outputs (concatenated float32, return order):
//   tl (B,A) | tb (B,A,4) | ts (B,A,C) | fg (B,A) | tgt (B,A)
//
// R1: removed global atomic histogram (65us same-cacheline serialization).
// R2: fix2 wave-parallel register scan (was 71.7us dependent-latency).
// R3 (regressed): select1 inside 32-block fix2 -> 32/256 CUs busy.
// R4: select1 full-grid; 5 kernels + memset = 74.5us.
// R5 (regressed, 250us): single cooperative kernel — grid.sync() costs
//     ~60-70us each on this stack (VALUBusy 9.4% x 250us = only ~23us of
//     real work). Kernel boundary (~5-7us) is CHEAPER than grid.sync.
// R6: R4 structure, 6 dispatches -> 3:
//     k_col: colKey + inline hasin -> needByte (drops inmask dep + memset);
//            re-zeroes cnt/ticket for graph-replay determinism.
//     k_sel: recomputes in-box bits locally (cheaper than HBM round-trip),
//            merges fix1 pair-list, plain-stores rowbits (single writer),
//            select1 argmax + LDS->global histogram, then last-block-of-
//            batch ticket (device atomics + threadfence, G12/G16) runs the
//            fix2 wave-register scan inline.
//     k_finalts: unchanged R4.
// ---------------------------------------------------------------------------

#define EPS_IN   1e-9f
#define IOU_EPS  1e-7f

// IoU exactly as reference (_iou_xyxy) with clip(.,0); fp contraction off so
// results are bit-identical across kernels and match plain IEEE numpy eval.
__device__ __forceinline__ float iou_pair(const float4 p, const float4 g) {
#pragma clang fp contract(off)
    float w1 = p.z - p.x;
    float h1 = (p.w - p.y) + IOU_EPS;
    float w2 = g.z - g.x;
    float h2 = (g.w - g.y) + IOU_EPS;
    float iw = fminf(p.z, g.z) - fmaxf(p.x, g.x);
    iw = fmaxf(iw, 0.0f);
    float ih = fminf(p.w, g.w) - fmaxf(p.y, g.y);
    ih = fmaxf(ih, 0.0f);
    float inter = iw * ih;
    float uni = w1 * h1 + w2 * h2 - inter + IOU_EPS;
    float r = inter / uni;
    return fmaxf(r, 0.0f);
}

// mask_gt dtype detection (int32 / f32 / u8), wave-uniform. mask[b][0] is
// always true (n_gt>=1) so each dtype is observable in the first nw words.
__device__ __forceinline__ int detect_mode(const void* mg, int nw) {
    const unsigned* w = (const unsigned*)mg;
    int lane = threadIdx.x & 63;
    int badI = 0, badF = 0;
    for (int i = lane; i < nw; i += 64) {
        unsigned v = w[i];
        badI |= (v > 1u);
        badF |= (v != 0u && v != 0x3F800000u);
    }
    unsigned long long bI = __ballot(badI != 0);
    unsigned long long bF = __ballot(badF != 0);
    return bI ? (bF ? 2 : 1) : 0;
}

__device__ __forceinline__ bool mask_at(const void* mg, int mode, int idx) {
    if (mode == 0) return ((const int*)mg)[idx] != 0;
    if (mode == 1) return ((const float*)mg)[idx] != 0.0f;
    return ((const unsigned char*)mg)[idx] != 0;
}

// K1: per (b,m) column. Re-zeroes cnt/ticket (replay determinism), then for
// masked columns: argmax_a overlaps -> colKey (first-index tiebreak key) +
// inline hasin (any anchor strictly inside) -> needByte (fix1 need flag).
__global__ void k_col(const float4* __restrict__ pdb, const float2* __restrict__ anc,
                      const float4* __restrict__ gtb, const void* mg, int nw,
                      unsigned long long* __restrict__ colKey,
                      unsigned char* __restrict__ needByte,
                      int* __restrict__ cnt, int* __restrict__ ticket,
                      int A, int M) {
    int b = blockIdx.y, m = blockIdx.x, tid = threadIdx.x;
    if (tid == 0) {
        cnt[b * M + m] = 0;
        if (m == 0) ticket[b] = 0;
    }
    int mode = detect_mode(mg, nw);
    if (!mask_at(mg, mode, b * M + m)) return;
    float4 g = gtb[b * M + m];
    size_t bA = (size_t)b * A;
    unsigned long long key = 0ull;
    int hasin = 0;
    for (int a = tid; a < A; a += 256) {
        float v = iou_pair(pdb[bA + a], g);
        unsigned long long k =
            ((unsigned long long)__float_as_uint(v) << 32) | (0xFFFFFFFFu - (unsigned)a);
        if (k > key) key = k;
        float2 an = anc[a];
        float mn = fminf(fminf(an.x - g.x, an.y - g.y), fminf(g.z - an.x, g.w - an.y));
        hasin |= (mn > EPS_IN);
    }
    __shared__ unsigned long long skey[4];
    __shared__ int sin_[4];
    int lane = tid & 63, wid = tid >> 6;
    for (int off = 32; off; off >>= 1) {
        unsigned long long o = __shfl_down(key, off);
        if (o > key) key = o;
        hasin |= __shfl_down(hasin, off);
    }
    if (lane == 0) { skey[wid] = key; sin_[wid] = hasin; }
    __syncthreads();
    if (tid == 0) {
        for (int i = 1; i < 4; i++) { if (skey[i] > key) key = skey[i]; hasin |= sin_[i]; }
        colKey[b * M + m] = key;
        needByte[b * M + m] = hasin ? 0 : 1;
    }
}

// K2: per (b, anchor-chunk). In-box bits recomputed locally; fix1 merged via
// per-batch pair list; rowbits plain-stored (single writer); select1 dedup
// argmax -> tgtfg; LDS histogram -> global cnt; last block of the batch
// (device-scope ticket) runs the fix2 wave-register scan inline.
__global__ void k_sel(const float4* __restrict__ pdb, const float2* __restrict__ anc,
                      const float4* __restrict__ gtb, const void* mg, int nw,
                      const unsigned long long* __restrict__ colKey,
                      const unsigned char* __restrict__ needByte,
                      unsigned* __restrict__ rowbits, int* __restrict__ tgtfg,
                      int* __restrict__ cnt, int* __restrict__ ticket,
                      int A, int M, int nCh) {
    int b = blockIdx.y, tid = threadIdx.x;
    int a = blockIdx.x * 256 + tid;
    int mode = detect_mode(mg, nw);
    __shared__ float4 sg[32];
    __shared__ unsigned char smg[32];
    __shared__ int fixA[32];
    __shared__ unsigned char fixG[32];
    __shared__ int sL;
    __shared__ int shist[32];
    __shared__ int sLast;
    if (tid < M) {
        sg[tid]  = gtb[b * M + tid];
        smg[tid] = mask_at(mg, mode, b * M + tid) ? 1 : 0;
    }
    if (tid < 32) shist[tid] = 0;
    __syncthreads();
    if (tid < 64) {
        bool needv = (tid < M) && smg[tid] && needByte[b * M + tid];
        unsigned nb = (unsigned)__ballot(needv);
        if (needv) {
            unsigned long long key = colKey[b * M + tid];
            int best = (int)(0xFFFFFFFFu - (unsigned)(key & 0xFFFFFFFFull));
            int pos = __popc(nb & ((1u << tid) - 1u));
            fixA[pos] = best; fixG[pos] = (unsigned char)tid;
        }
        if (tid == 0) sL = __popc(nb);
    }
    __syncthreads();
    size_t bA = (size_t)b * A;
    if (a < A) {
        float2 an = anc[a];
        unsigned bits = 0u;
        for (int m = 0; m < M; m++) {
            float4 g = sg[m];
            float mn = fminf(fminf(an.x - g.x, an.y - g.y), fminf(g.z - an.x, g.w - an.y));
            if (mn > EPS_IN && smg[m]) bits |= (1u << m);
        }
        int L = sL;
        for (int j = 0; j < L; j++) if (fixA[j] == a) bits |= (1u << fixG[j]);
        rowbits[bA + a] = bits;                    // plain store (single writer)
        int pc = __popc(bits);
        int t;
        if (pc > 1) {
            float4 p = pdb[bA + a];
            float bv = -1.0f; int bm = 0;
            for (int m = 0; m < M; m++) {
                float v = iou_pair(p, sg[m]);
                if (v > bv) { bv = v; bm = m; }
            }
            t = bm;
        } else if (pc == 1) t = __ffs(bits) - 1;
        else t = -1;
        tgtfg[bA + a] = t;
        if (t >= 0) atomicAdd(&shist[t], 1);
    }
    __syncthreads();
    if (tid < 32 && shist[tid]) atomicAdd(&cnt[b * M + tid], shist[tid]);
    __threadfence();                               // release: all our writes
    __syncthreads();
    if (tid == 0) {
        int old = atomicAdd(&ticket[b], 1);        // device-scope arrival
        sLast = (old == nCh - 1) ? 1 : 0;
    }
    __syncthreads();
    if (!sLast) return;
    __threadfence();                               // acquire: see all writes
    if (tid >= 64) return;
    // fix2: order-dependent 32-step scan, wave-parallel in registers.
    bool mv = (tid < M) && smg[tid];
    int best = -1;
    if (mv) {
        unsigned long long key = colKey[b * M + tid];
        best = (int)(0xFFFFFFFFu - (unsigned)(key & 0xFFFFFFFFull));
    }
    unsigned maskbits = (unsigned)__ballot(mv);
    int myBest = (tid < 32) ? best : -1;
    int myCnt  = (tid < 32 && tid < M) ? cnt[b * M + tid] : 0;
    int myPre  = (myBest >= 0) ? tgtfg[bA + myBest] : -1;
    unsigned myEq = 0u;
    for (int g2 = 0; g2 < 32; g2++) {
        int bb = __shfl(myBest, g2);
        if (bb == myBest) myEq |= (1u << g2);
    }
    unsigned applied = 0u;
    for (int g = 0; g < M; g++) {
        int cg = __shfl(myCnt, g);
        if (((maskbits >> g) & 1u) && cg == 0) {
            int aa      = __shfl(myBest, g);
            unsigned em = __shfl(myEq, g);
            unsigned x  = applied & em;
            int old;
            if (x) old = 31 - __clz(x);      // last earlier step that took this anchor
            else   old = __shfl(myPre, g);   // select1's owner (-1 = background)
            if (tid == old) myCnt--;
            if (tid == g)   myCnt++;
            applied |= (1u << g);
            if (tid == 0)
                atomicOr(&rowbits[bA + aa], 1u << g);   // fire-and-forget
        }
    }
}

// K3: final select (#2) + all outputs. Per-anchor tgt/fg/ov from rowbits
// (pc>1 -> full-row argmax, invariant to extra bits), single pd_scores
// gather, scalar outputs; block-cooperative coalesced float4 ts write.
__global__ void k_finalts(const float* __restrict__ pds, const float4* __restrict__ pdb,
                          const float4* __restrict__ gtb, const int* __restrict__ gtl,
                          const unsigned* __restrict__ rowbits, float* __restrict__ out,
                          int A, int M, int C, int B) {
    int b = blockIdx.y;
    int base = blockIdx.x * 256;
    int tid = threadIdx.x;
    int a = base + tid;
    __shared__ float4 sg[32];
    __shared__ int slab[32];
    __shared__ float snorm[256];
    __shared__ int stl[256];
    if (tid < M) { sg[tid] = gtb[b * M + tid]; slab[tid] = gtl[b * M + tid]; }
    __syncthreads();
    size_t BA = (size_t)B * A;
    if (a < A) {
        size_t idx = (size_t)b * A + a;
        unsigned bits = rowbits[idx];
        int pc = __popc(bits);
        int tgt, fg; float ov = 0.0f;
        float4 p = pdb[idx];
        if (pc > 1) {
            float bv = -1.0f; int bm = 0;
            for (int m = 0; m < M; m++) {
                float v = iou_pair(p, sg[m]);
                if (v > bv) { bv = v; bm = m; }
            }
            tgt = bm; fg = 1; ov = bv;
        } else if (pc == 1) {
            tgt = __ffs(bits) - 1; fg = 1;
            ov = iou_pair(p, sg[tgt]);
        } else { tgt = 0; fg = 0; }
        int lab = slab[tgt];
        int tl = min(max(lab, 0), C);            // clip(., 0, NUM_CLASSES)
        float norm = 0.0f;
        if (fg) {
            int li = (lab >= 0 && lab < C) ? lab : 0;
            float cls = pds[idx * (size_t)C + li];
            float ov6 = powf(ov, 6.0f);          // overlaps ** BETA
            float v = cls * ov6;                 // align_metric at (a, tgt)
            norm = v * ov / (v + 1e-9f);         // pam*pov/(pam+eps)
        }
        out[idx] = (float)tl;                                // tl
        ((float4*)(out + BA))[idx] = sg[tgt];                // tb
        out[BA * (size_t)(5 + C) + idx] = fg ? 1.0f : 0.0f;  // fg
        out[BA * (size_t)(6 + C) + idx] = (float)tgt;        // tgt
        snorm[tid] = norm;
        stl[tid] = tl;
    }
    __syncthreads();
    int cntA = min(256, A - base);
    int rowf4 = C >> 2;
    int nf4 = cntA * rowf4;
    float4* tsb = (float4*)(out + BA * 5 + ((size_t)b * A + base) * C);
    int q = 256 / rowf4, r = 256 - q * rowf4;
    int row = tid / rowf4;
    int c4  = tid - row * rowf4;
    for (int i = tid; i < nf4; i += 256) {
        float nv = snorm[row];
        int tl   = stl[row];
        int cb = c4 * 4;
        float4 v;
        v.x = (tl == cb + 0) ? nv : 0.0f;
        v.y = (tl == cb + 1) ? nv : 0.0f;
        v.z = (tl == cb + 2) ? nv : 0.0f;
        v.w = (tl == cb + 3) ? nv : 0.0f;
        tsb[i] = v;
        row += q; c4 += r;
        if (c4 >= rowf4) { c4 -= rowf4; row++; }
    }
}

extern "C" void kernel_launch(void* const* d_in, const int* in_sizes, int n_in,
                              void* d_out, int out_size, void* d_ws, size_t ws_size,
                              hipStream_t stream) {
    const float*  pd_scores = (const float*)d_in[0];
    const float4* pd_bboxes = (const float4*)d_in[1];
    const float2* anc       = (const float2*)d_in[2];
    const int*    gt_labels = (const int*)d_in[3];
    const float4* gt_bboxes = (const float4*)d_in[4];
    const void*   mask_gt   = d_in[5];

    int A = in_sizes[2] / 2;
    int B = in_sizes[1] / (A * 4);
    int M = in_sizes[3] / B;
    int C = (int)((long long)in_sizes[0] / ((long long)B * A));
    int nCh = (A + 255) / 256;
    int nw = (B * M) / 4; if (nw > 256) nw = 256;

    char* wp = (char*)d_ws;
    auto carve = [&](size_t bytes) -> char* {
        char* r = wp; wp += (bytes + 255) & ~(size_t)255; return r;
    };
    unsigned* rowbits          = (unsigned*)carve((size_t)B * A * 4);
    int* tgtfg                 = (int*)carve((size_t)B * A * 4);
    unsigned long long* colKey = (unsigned long long*)carve((size_t)B * M * 8);
    int* cnt                   = (int*)carve((size_t)B * M * 4);
    unsigned char* needByte    = (unsigned char*)carve((size_t)B * M);
    int* ticket                = (int*)carve((size_t)B * 4);

    float* out = (float*)d_out;

    k_col<<<dim3(M, B), 256, 0, stream>>>(pd_bboxes, anc, gt_bboxes, mask_gt, nw,
                                          colKey, needByte, cnt, ticket, A, M);
    k_sel<<<dim3(nCh, B), 256, 0, stream>>>(pd_bboxes, anc, gt_bboxes, mask_gt, nw,
                                            colKey, needByte, rowbits, tgtfg,
                                            cnt, ticket, A, M, nCh);
    k_finalts<<<dim3(nCh, B), 256, 0, stream>>>(pd_scores, pd_bboxes, gt_bboxes,
                                                gt_labels, rowbits, out, A, M, C, B);
}

// Round 8
// 59.939 us; speedup vs baseline: 4.1603x; 2.1267x over previous
//
#include <hip/hip_runtime.h>

// ---------------------------------------------------------------------------
// TaskAlignedAssigner (YOLO TAL) for MI355X — 4 dispatches, no fences.
// B=32, A=8400, M=32, C=80 (derived at runtime; M<=32 so a gt-column mask
// fits one uint32 per anchor; C%4==0 assumed for float4 ts writes).
//
// Outputs (concatenated float32, return order):
//   tl (B,A) | tb (B,A,4) | ts (B,A,C) | fg (B,A) | tgt (B,A)
//
// R1: removed global atomic histogram (65us same-cacheline serialization).
// R2: fix2 wave-parallel register scan (was 71.7us dependent-latency).
// R3 (regressed): select1 inside 32-block fix2 -> 32/256 CUs busy.
// R4: select1 full-grid; 5 kernels + memset = 74.5us.
// R5 (regressed, 250us): cooperative kernel — grid.sync ~60-70us each.
// R6 (regressed, 127us): ticket+__threadfence in k_sel — device-scope
//     release fence on non-coherent per-XCD L2s costs ~90us across 1056
//     blocks (k_sel alone 97us at 7% VALUBusy). Lesson: express cross-block
//     deps as DISPATCH BOUNDARIES; never fence the full grid.
// R7: R6 minus ticket/fence; fix2 back to its own tiny dispatch (B x 64)
//     reading the prebuilt cnt (32 loads, no histogram pass). 4 dispatches:
//     k_col -> k_sel -> k_fix2 -> k_finalts.
// ---------------------------------------------------------------------------

#define EPS_IN   1e-9f
#define IOU_EPS  1e-7f

// IoU exactly as reference (_iou_xyxy) with clip(.,0); fp contraction off so
// results are bit-identical across kernels and match plain IEEE numpy eval.
__device__ __forceinline__ float iou_pair(const float4 p, const float4 g) {
#pragma clang fp contract(off)
    float w1 = p.z - p.x;
    float h1 = (p.w - p.y) + IOU_EPS;
    float w2 = g.z - g.x;
    float h2 = (g.w - g.y) + IOU_EPS;
    float iw = fminf(p.z, g.z) - fmaxf(p.x, g.x);
    iw = fmaxf(iw, 0.0f);
    float ih = fminf(p.w, g.w) - fmaxf(p.y, g.y);
    ih = fmaxf(ih, 0.0f);
    float inter = iw * ih;
    float uni = w1 * h1 + w2 * h2 - inter + IOU_EPS;
    float r = inter / uni;
    return fmaxf(r, 0.0f);
}

// mask_gt dtype detection (int32 / f32 / u8), wave-uniform. mask[b][0] is
// always true (n_gt>=1) so each dtype is observable in the first nw words.
__device__ __forceinline__ int detect_mode(const void* mg, int nw) {
    const unsigned* w = (const unsigned*)mg;
    int lane = threadIdx.x & 63;
    int badI = 0, badF = 0;
    for (int i = lane; i < nw; i += 64) {
        unsigned v = w[i];
        badI |= (v > 1u);
        badF |= (v != 0u && v != 0x3F800000u);
    }
    unsigned long long bI = __ballot(badI != 0);
    unsigned long long bF = __ballot(badF != 0);
    return bI ? (bF ? 2 : 1) : 0;
}

__device__ __forceinline__ bool mask_at(const void* mg, int mode, int idx) {
    if (mode == 0) return ((const int*)mg)[idx] != 0;
    if (mode == 1) return ((const float*)mg)[idx] != 0.0f;
    return ((const unsigned char*)mg)[idx] != 0;
}

// K1: per (b,m) column. Zeroes cnt (replay determinism, no memset dispatch);
// for masked columns: argmax_a overlaps -> colKey (first-index tiebreak) +
// inline hasin (any anchor strictly inside) -> needByte (fix1 need flag).
__global__ void k_col(const float4* __restrict__ pdb, const float2* __restrict__ anc,
                      const float4* __restrict__ gtb, const void* mg, int nw,
                      unsigned long long* __restrict__ colKey,
                      unsigned char* __restrict__ needByte,
                      int* __restrict__ cnt, int A, int M) {
    int b = blockIdx.y, m = blockIdx.x, tid = threadIdx.x;
    if (tid == 0) cnt[b * M + m] = 0;
    int mode = detect_mode(mg, nw);
    if (!mask_at(mg, mode, b * M + m)) return;
    float4 g = gtb[b * M + m];
    size_t bA = (size_t)b * A;
    unsigned long long key = 0ull;
    int hasin = 0;
    for (int a = tid; a < A; a += 256) {
        float v = iou_pair(pdb[bA + a], g);
        unsigned long long k =
            ((unsigned long long)__float_as_uint(v) << 32) | (0xFFFFFFFFu - (unsigned)a);
        if (k > key) key = k;
        float2 an = anc[a];
        float mn = fminf(fminf(an.x - g.x, an.y - g.y), fminf(g.z - an.x, g.w - an.y));
        hasin |= (mn > EPS_IN);
    }
    __shared__ unsigned long long skey[4];
    __shared__ int sin_[4];
    int lane = tid & 63, wid = tid >> 6;
    for (int off = 32; off; off >>= 1) {
        unsigned long long o = __shfl_down(key, off);
        if (o > key) key = o;
        hasin |= __shfl_down(hasin, off);
    }
    if (lane == 0) { skey[wid] = key; sin_[wid] = hasin; }
    __syncthreads();
    if (tid == 0) {
        for (int i = 1; i < 4; i++) { if (skey[i] > key) key = skey[i]; hasin |= sin_[i]; }
        colKey[b * M + m] = key;
        needByte[b * M + m] = hasin ? 0 : 1;
    }
}

// K2: per (b, anchor-chunk). In-box bits recomputed locally (cheaper than an
// HBM round-trip + extra dispatch); fix1 merged via per-batch pair list;
// rowbits plain-stored (single writer); select1 dedup argmax -> tgtfg;
// guarded LDS histogram flush -> global cnt. No fences, no tickets.
__global__ void k_sel(const float4* __restrict__ pdb, const float2* __restrict__ anc,
                      const float4* __restrict__ gtb, const void* mg, int nw,
                      const unsigned long long* __restrict__ colKey,
                      const unsigned char* __restrict__ needByte,
                      unsigned* __restrict__ rowbits, int* __restrict__ tgtfg,
                      int* __restrict__ cnt, int A, int M) {
    int b = blockIdx.y, tid = threadIdx.x;
    int a = blockIdx.x * 256 + tid;
    int mode = detect_mode(mg, nw);
    __shared__ float4 sg[32];
    __shared__ unsigned char smg[32];
    __shared__ int fixA[32];
    __shared__ unsigned char fixG[32];
    __shared__ int sL;
    __shared__ int shist[32];
    if (tid < M) {
        sg[tid]  = gtb[b * M + tid];
        smg[tid] = mask_at(mg, mode, b * M + tid) ? 1 : 0;
    }
    if (tid < 32) shist[tid] = 0;
    __syncthreads();
    if (tid < 64) {
        bool needv = (tid < M) && smg[tid] && needByte[b * M + tid];
        unsigned nb = (unsigned)__ballot(needv);
        if (needv) {
            unsigned long long key = colKey[b * M + tid];
            int best = (int)(0xFFFFFFFFu - (unsigned)(key & 0xFFFFFFFFull));
            int pos = __popc(nb & ((1u << tid) - 1u));
            fixA[pos] = best; fixG[pos] = (unsigned char)tid;
        }
        if (tid == 0) sL = __popc(nb);
    }
    __syncthreads();
    size_t bA = (size_t)b * A;
    if (a < A) {
        float2 an = anc[a];
        unsigned bits = 0u;
        for (int m = 0; m < M; m++) {
            float4 g = sg[m];
            float mn = fminf(fminf(an.x - g.x, an.y - g.y), fminf(g.z - an.x, g.w - an.y));
            if (mn > EPS_IN && smg[m]) bits |= (1u << m);
        }
        int L = sL;
        for (int j = 0; j < L; j++) if (fixA[j] == a) bits |= (1u << fixG[j]);
        rowbits[bA + a] = bits;                    // plain store (single writer)
        int pc = __popc(bits);
        int t;
        if (pc > 1) {
            float4 p = pdb[bA + a];
            float bv = -1.0f; int bm = 0;
            for (int m = 0; m < M; m++) {
                float v = iou_pair(p, sg[m]);
                if (v > bv) { bv = v; bm = m; }
            }
            t = bm;
        } else if (pc == 1) t = __ffs(bits) - 1;
        else t = -1;
        tgtfg[bA + a] = t;
        if (t >= 0) atomicAdd(&shist[t], 1);
    }
    __syncthreads();
    if (tid < 32 && shist[tid]) atomicAdd(&cnt[b * M + tid], shist[tid]);
}

// K3: fix2 — order-dependent per-gt reassignment scan. One block per batch,
// 64 threads: prefetch cnt/colKey/mask/tgtfg[best] in parallel, then the
// 32-step scan runs wave-parallel in registers (shfl-only dependencies);
// global side effects are <=32 fire-and-forget atomicOrs.
__global__ void k_fix2(const void* mg, int nw,
                       const unsigned long long* __restrict__ colKey,
                       const int* __restrict__ cnt, const int* __restrict__ tgtfg,
                       unsigned* __restrict__ rowbits, int A, int M) {
    int b = blockIdx.x, tid = threadIdx.x;   // 64 threads
    int mode = detect_mode(mg, nw);
    size_t bA = (size_t)b * A;
    bool mv = (tid < M) && mask_at(mg, mode, b * M + tid);
    int best = -1;
    if (mv) {
        unsigned long long key = colKey[b * M + tid];
        best = (int)(0xFFFFFFFFu - (unsigned)(key & 0xFFFFFFFFull));
    }
    unsigned maskbits = (unsigned)__ballot(mv);
    int myBest = (tid < 32) ? best : -1;
    int myCnt  = (tid < M && mv) ? cnt[b * M + tid] : 0;
    int myPre  = (myBest >= 0) ? tgtfg[bA + myBest] : -1;
    unsigned myEq = 0u;
    for (int g2 = 0; g2 < 32; g2++) {
        int bb = __shfl(myBest, g2);
        if (bb == myBest) myEq |= (1u << g2);
    }
    unsigned applied = 0u;
    for (int g = 0; g < M; g++) {
        int cg = __shfl(myCnt, g);
        if (((maskbits >> g) & 1u) && cg == 0) {
            int aa      = __shfl(myBest, g);
            unsigned em = __shfl(myEq, g);
            unsigned x  = applied & em;
            int old;
            if (x) old = 31 - __clz(x);      // last earlier step that took this anchor
            else   old = __shfl(myPre, g);   // select1's owner (-1 = background)
            if (tid == old) myCnt--;
            if (tid == g)   myCnt++;
            applied |= (1u << g);
            if (tid == 0)
                atomicOr(&rowbits[bA + aa], 1u << g);   // fire-and-forget
        }
    }
}

// K4: final select (#2) + all outputs. Per-anchor tgt/fg/ov from rowbits
// (pc>1 -> full-row argmax, invariant to extra bits), single pd_scores
// gather, scalar outputs; block-cooperative coalesced float4 ts write.
__global__ void k_finalts(const float* __restrict__ pds, const float4* __restrict__ pdb,
                          const float4* __restrict__ gtb, const int* __restrict__ gtl,
                          const unsigned* __restrict__ rowbits, float* __restrict__ out,
                          int A, int M, int C, int B) {
    int b = blockIdx.y;
    int base = blockIdx.x * 256;
    int tid = threadIdx.x;
    int a = base + tid;
    __shared__ float4 sg[32];
    __shared__ int slab[32];
    __shared__ float snorm[256];
    __shared__ int stl[256];
    if (tid < M) { sg[tid] = gtb[b * M + tid]; slab[tid] = gtl[b * M + tid]; }
    __syncthreads();
    size_t BA = (size_t)B * A;
    if (a < A) {
        size_t idx = (size_t)b * A + a;
        unsigned bits = rowbits[idx];
        int pc = __popc(bits);
        int tgt, fg; float ov = 0.0f;
        float4 p = pdb[idx];
        if (pc > 1) {
            float bv = -1.0f; int bm = 0;
            for (int m = 0; m < M; m++) {
                float v = iou_pair(p, sg[m]);
                if (v > bv) { bv = v; bm = m; }
            }
            tgt = bm; fg = 1; ov = bv;
        } else if (pc == 1) {
            tgt = __ffs(bits) - 1; fg = 1;
            ov = iou_pair(p, sg[tgt]);
        } else { tgt = 0; fg = 0; }
        int lab = slab[tgt];
        int tl = min(max(lab, 0), C);            // clip(., 0, NUM_CLASSES)
        float norm = 0.0f;
        if (fg) {
            int li = (lab >= 0 && lab < C) ? lab : 0;
            float cls = pds[idx * (size_t)C + li];
            float ov6 = powf(ov, 6.0f);          // overlaps ** BETA
            float v = cls * ov6;                 // align_metric at (a, tgt)
            norm = v * ov / (v + 1e-9f);         // pam*pov/(pam+eps)
        }
        out[idx] = (float)tl;                                // tl
        ((float4*)(out + BA))[idx] = sg[tgt];                // tb
        out[BA * (size_t)(5 + C) + idx] = fg ? 1.0f : 0.0f;  // fg
        out[BA * (size_t)(6 + C) + idx] = (float)tgt;        // tgt
        snorm[tid] = norm;
        stl[tid] = tl;
    }
    __syncthreads();
    int cntA = min(256, A - base);
    int rowf4 = C >> 2;
    int nf4 = cntA * rowf4;
    float4* tsb = (float4*)(out + BA * 5 + ((size_t)b * A + base) * C);
    int q = 256 / rowf4, r = 256 - q * rowf4;
    int row = tid / rowf4;
    int c4  = tid - row * rowf4;
    for (int i = tid; i < nf4; i += 256) {
        float nv = snorm[row];
        int tl   = stl[row];
        int cb = c4 * 4;
        float4 v;
        v.x = (tl == cb + 0) ? nv : 0.0f;
        v.y = (tl == cb + 1) ? nv : 0.0f;
        v.z = (tl == cb + 2) ? nv : 0.0f;
        v.w = (tl == cb + 3) ? nv : 0.0f;
        tsb[i] = v;
        row += q; c4 += r;
        if (c4 >= rowf4) { c4 -= rowf4; row++; }
    }
}

extern "C" void kernel_launch(void* const* d_in, const int* in_sizes, int n_in,
                              void* d_out, int out_size, void* d_ws, size_t ws_size,
                              hipStream_t stream) {
    const float*  pd_scores = (const float*)d_in[0];
    const float4* pd_bboxes = (const float4*)d_in[1];
    const float2* anc       = (const float2*)d_in[2];
    const int*    gt_labels = (const int*)d_in[3];
    const float4* gt_bboxes = (const float4*)d_in[4];
    const void*   mask_gt   = d_in[5];

    int A = in_sizes[2] / 2;
    int B = in_sizes[1] / (A * 4);
    int M = in_sizes[3] / B;
    int C = (int)((long long)in_sizes[0] / ((long long)B * A));
    int nCh = (A + 255) / 256;
    int nw = (B * M) / 4; if (nw > 256) nw = 256;

    char* wp = (char*)d_ws;
    auto carve = [&](size_t bytes) -> char* {
        char* r = wp; wp += (bytes + 255) & ~(size_t)255; return r;
    };
    unsigned* rowbits          = (unsigned*)carve((size_t)B * A * 4);
    int* tgtfg                 = (int*)carve((size_t)B * A * 4);
    unsigned long long* colKey = (unsigned long long*)carve((size_t)B * M * 8);
    int* cnt                   = (int*)carve((size_t)B * M * 4);
    unsigned char* needByte    = (unsigned char*)carve((size_t)B * M);

    float* out = (float*)d_out;

    k_col<<<dim3(M, B), 256, 0, stream>>>(pd_bboxes, anc, gt_bboxes, mask_gt, nw,
                                          colKey, needByte, cnt, A, M);
    k_sel<<<dim3(nCh, B), 256, 0, stream>>>(pd_bboxes, anc, gt_bboxes, mask_gt, nw,
                                            colKey, needByte, rowbits, tgtfg, cnt, A, M);
    k_fix2<<<B, 64, 0, stream>>>(mask_gt, nw, colKey, cnt, tgtfg, rowbits, A, M);
    k_finalts<<<dim3(nCh, B), 256, 0, stream>>>(pd_scores, pd_bboxes, gt_bboxes,
                                                gt_labels, rowbits, out, A, M, C, B);
}

// Round 9
// 53.327 us; speedup vs baseline: 4.6761x; 1.1240x over previous
//
#include <hip/hip_runtime.h>

// ---------------------------------------------------------------------------
// TaskAlignedAssigner (YOLO TAL) for MI355X — 2 dispatches.
// B=32, A=8400, M=32, C=80 (derived at runtime; M<=32 so a gt-column mask
// fits one uint32 per anchor; C%4==0 assumed for float4 ts writes).
//
// Outputs (concatenated float32, return order):
//   tl (B,A) | tb (B,A,4) | ts (B,A,C) | fg (B,A) | tgt (B,A)
//
// R1: removed global atomic histogram (65us same-cacheline serialization).
// R2: fix2 wave-parallel register scan (was 71.7us dependent-latency).
// R3 (regressed): select1 inside 32-block fix2 -> 32/256 CUs busy.
// R4: select1 full-grid; 5 kernels + memset = 74.5us.
// R5 (regressed, 250us): cooperative kernel — grid.sync ~60-70us each.
// R6 (regressed, 127us): ticket+__threadfence — ~90us of L2 writeback.
// R7: 4 dispatches, no fences: 59.9us. Boundary cost calibrated ~7us each.
// R8: 2 dispatches. fix1 deferred out of k_sel -> column pass and anchor
//     pass are independent -> merged into k_phase1 (grid (M+nCh) x B).
//     Histogram via per-chunk plain stores (deterministic, no zeroing).
//     k_final recomputes the serial tail per block (fix1 groups + count
//     adjust + fix2 register scan -> <=64-entry LDS override list), then
//     applies overrides in the per-anchor output pass. No global atomics.
// ---------------------------------------------------------------------------

#define EPS_IN   1e-9f
#define IOU_EPS  1e-7f

// IoU exactly as reference (_iou_xyxy) with clip(.,0); fp contraction off so
// results are bit-identical across kernels and match plain IEEE numpy eval.
__device__ __forceinline__ float iou_pair(const float4 p, const float4 g) {
#pragma clang fp contract(off)
    float w1 = p.z - p.x;
    float h1 = (p.w - p.y) + IOU_EPS;
    float w2 = g.z - g.x;
    float h2 = (g.w - g.y) + IOU_EPS;
    float iw = fminf(p.z, g.z) - fmaxf(p.x, g.x);
    iw = fmaxf(iw, 0.0f);
    float ih = fminf(p.w, g.w) - fmaxf(p.y, g.y);
    ih = fmaxf(ih, 0.0f);
    float inter = iw * ih;
    float uni = w1 * h1 + w2 * h2 - inter + IOU_EPS;
    float r = inter / uni;
    return fmaxf(r, 0.0f);
}

// mask_gt dtype detection (int32 / f32 / u8), wave-uniform. mask[b][0] is
// always true (n_gt>=1) so each dtype is observable in the first nw words.
__device__ __forceinline__ int detect_mode(const void* mg, int nw) {
    const unsigned* w = (const unsigned*)mg;
    int lane = threadIdx.x & 63;
    int badI = 0, badF = 0;
    for (int i = lane; i < nw; i += 64) {
        unsigned v = w[i];
        badI |= (v > 1u);
        badF |= (v != 0u && v != 0x3F800000u);
    }
    unsigned long long bI = __ballot(badI != 0);
    unsigned long long bF = __ballot(badF != 0);
    return bI ? (bF ? 2 : 1) : 0;
}

__device__ __forceinline__ bool mask_at(const void* mg, int mode, int idx) {
    if (mode == 0) return ((const int*)mg)[idx] != 0;
    if (mode == 1) return ((const float*)mg)[idx] != 0.0f;
    return ((const unsigned char*)mg)[idx] != 0;
}

// K1: merged column+anchor pass (independent halves, disjoint outputs).
//  blockIdx.x <  M  : column task (b,m): masked -> colKey (argmax_a overlaps,
//                     first-index tiebreak) + hasin -> needByte.
//  blockIdx.x >= M  : chunk task (b,ch): in-box bits -> rowbits0 (plain),
//                     select1 (no fix1) -> tgt0, per-chunk histogram ->
//                     cntChunk[b][ch][32] (plain stores, no atomics).
__global__ void k_phase1(const float4* __restrict__ pdb, const float2* __restrict__ anc,
                         const float4* __restrict__ gtb, const void* mg, int nw,
                         unsigned long long* __restrict__ colKey,
                         unsigned char* __restrict__ needByte,
                         unsigned* __restrict__ rowbits0, short* __restrict__ tgt0,
                         int* __restrict__ cntChunk,
                         int A, int M, int nCh) {
    int b = blockIdx.y, tid = threadIdx.x;
    int mode = detect_mode(mg, nw);
    size_t bA = (size_t)b * A;

    if ((int)blockIdx.x < M) {
        // ---- column task ----
        int m = blockIdx.x;
        if (!mask_at(mg, mode, b * M + m)) return;
        float4 g = gtb[b * M + m];
        unsigned long long key = 0ull;
        int hasin = 0;
        for (int a = tid; a < A; a += 256) {
            float v = iou_pair(pdb[bA + a], g);
            unsigned long long k =
                ((unsigned long long)__float_as_uint(v) << 32) | (0xFFFFFFFFu - (unsigned)a);
            if (k > key) key = k;
            float2 an = anc[a];
            float mn = fminf(fminf(an.x - g.x, an.y - g.y), fminf(g.z - an.x, g.w - an.y));
            hasin |= (mn > EPS_IN);
        }
        __shared__ unsigned long long skey[4];
        __shared__ int sin_[4];
        int lane = tid & 63, wid = tid >> 6;
        for (int off = 32; off; off >>= 1) {
            unsigned long long o = __shfl_down(key, off);
            if (o > key) key = o;
            hasin |= __shfl_down(hasin, off);
        }
        if (lane == 0) { skey[wid] = key; sin_[wid] = hasin; }
        __syncthreads();
        if (tid == 0) {
            for (int i = 1; i < 4; i++) { if (skey[i] > key) key = skey[i]; hasin |= sin_[i]; }
            colKey[b * M + m] = key;
            needByte[b * M + m] = hasin ? 0 : 1;
        }
    } else {
        // ---- chunk task ----
        int ch = blockIdx.x - M;
        int a = ch * 256 + tid;
        __shared__ float4 sg[32];
        __shared__ unsigned char smg[32];
        __shared__ int shist[32];
        if (tid < M) {
            sg[tid]  = gtb[b * M + tid];
            smg[tid] = mask_at(mg, mode, b * M + tid) ? 1 : 0;
        }
        if (tid < 32) shist[tid] = 0;
        __syncthreads();
        if (a < A) {
            float2 an = anc[a];
            unsigned bits = 0u;
            for (int m = 0; m < M; m++) {
                float4 g = sg[m];
                float mn = fminf(fminf(an.x - g.x, an.y - g.y), fminf(g.z - an.x, g.w - an.y));
                if (mn > EPS_IN && smg[m]) bits |= (1u << m);
            }
            rowbits0[bA + a] = bits;
            int pc = __popc(bits);
            int t;
            if (pc > 1) {
                float4 p = pdb[bA + a];
                float bv = -1.0f; int bm = 0;
                for (int m = 0; m < M; m++) {
                    float v = iou_pair(p, sg[m]);
                    if (v > bv) { bv = v; bm = m; }
                }
                t = bm;
            } else if (pc == 1) t = __ffs(bits) - 1;
            else t = -1;
            tgt0[bA + a] = (short)t;
            if (t >= 0) atomicAdd(&shist[t], 1);
        }
        __syncthreads();
        if (tid < 32) cntChunk[((size_t)b * nCh + ch) * 32 + tid] = shist[tid];
    }
}

// K2: per-block serial-tail recompute + final select + all outputs.
// Prologue (first wave): cnt0 = sum cntChunk; fix1 groups (needy gts ->
// best anchor, recompute that anchor's select1 tgt via 32-lane IoU argmax,
// adjust counts, update pre-owners); fix2 32-step register scan; overrides
// collected in LDS (<=64 pairs). Main: per-anchor bits = rowbits0 |
// overrides -> select2 -> outputs; block-cooperative float4 ts write.
__global__ void k_final(const float* __restrict__ pds, const float4* __restrict__ pdb,
                        const float4* __restrict__ gtb, const int* __restrict__ gtl,
                        const void* mg, int nw,
                        const unsigned long long* __restrict__ colKey,
                        const unsigned char* __restrict__ needByte,
                        const unsigned* __restrict__ rowbits0,
                        const short* __restrict__ tgt0,
                        const int* __restrict__ cntChunk,
                        float* __restrict__ out,
                        int A, int M, int C, int B, int nCh) {
    int b = blockIdx.y;
    int base = blockIdx.x * 256;
    int tid = threadIdx.x;
    int mode = detect_mode(mg, nw);
    size_t bA = (size_t)b * A;
    __shared__ float4 sg[32];
    __shared__ int slab[32];
    __shared__ int ovrA[64];
    __shared__ unsigned ovrBits[64];
    __shared__ int sNov;
    __shared__ float snorm[256];
    __shared__ int stl[256];
    if (tid < M) { sg[tid] = gtb[b * M + tid]; slab[tid] = gtl[b * M + tid]; }
    __syncthreads();

    if (tid < 64) {
        // ---- lane state (lane g<32 owns gt g) ----
        bool mv = false, needv = false;
        int best = -1, c0 = 0;
        if (tid < M) mv = mask_at(mg, mode, b * M + tid);
        if (mv) {
            unsigned long long key = colKey[b * M + tid];
            best = (int)(0xFFFFFFFFu - (unsigned)(key & 0xFFFFFFFFull));
            needv = (needByte[b * M + tid] != 0);
        }
        if (tid < 32) {
            for (int ch = 0; ch < nCh; ch++)
                c0 += cntChunk[((size_t)b * nCh + ch) * 32 + tid];
        }
        int myPre = (mv && best >= 0) ? (int)tgt0[bA + best] : -1;
        unsigned maskbits = (unsigned)__ballot(mv);
        unsigned needBits = (unsigned)__ballot(needv);
        unsigned myEq = 0u;
        for (int g2 = 0; g2 < 32; g2++) {
            int bb = __shfl(best, g2);
            if (bb == best) myEq |= (1u << g2);
        }
        int nov = 0;
        // ---- fix1: groups of needy gts sharing the same best anchor ----
        unsigned rem = needBits;
        while (rem) {
            int gl = __ffs(rem) - 1;                       // group leader
            unsigned em = __shfl(myEq, gl) & needBits;     // group members
            rem &= ~em;
            int aF = __shfl(best, gl);
            unsigned addb = em;                            // bits added to aF
            unsigned bits0 = rowbits0[bA + aF];
            unsigned bits1 = bits0 | addb;
            int t1;
            if (__popc(bits1) > 1) {
                // select1 recompute: full-row IoU argmax (first-max tiebreak)
                float4 p = pdb[bA + aF];
                unsigned long long kk = 0ull;
                if (tid < M) {
                    float v = iou_pair(p, sg[tid]);
                    kk = ((unsigned long long)__float_as_uint(v) << 32) |
                         (0xFFFFFFFFu - (unsigned)tid);
                }
                for (int off = 32; off; off >>= 1) {
                    unsigned long long o = __shfl_down(kk, off);
                    if (o > kk) kk = o;
                }
                kk = __shfl(kk, 0);
                t1 = (int)(0xFFFFFFFFu - (unsigned)(kk & 0xFFFFFFFFull));
            } else {
                t1 = __ffs(bits1) - 1;                     // bits0 was empty
            }
            int t0a = __shfl(myPre, gl);                   // tgt0[aF]
            if (tid == t0a && t0a >= 0) c0--;              // count adjust
            if (tid == t1) c0++;
            if (best == aF) myPre = t1;                    // new pre-owner
            if (tid == 0) { ovrA[nov] = aF; ovrBits[nov] = addb; }
            nov++;
        }
        // ---- fix2: order-dependent 32-step scan in registers ----
        unsigned applied = 0u;
        for (int g = 0; g < M; g++) {
            int cg = __shfl(c0, g);
            if (((maskbits >> g) & 1u) && cg == 0) {
                int aa      = __shfl(best, g);
                unsigned em = __shfl(myEq, g);
                unsigned x  = applied & em;
                int old;
                if (x) old = 31 - __clz(x);    // last earlier step took this anchor
                else   old = __shfl(myPre, g); // owner after fix1 (-1 = background)
                if (tid == old) c0--;
                if (tid == g)   c0++;
                applied |= (1u << g);
                if (tid == 0) { ovrA[nov] = aa; ovrBits[nov] = 1u << g; }
                nov++;
            }
        }
        if (tid == 0) sNov = nov;
    }
    __syncthreads();

    // ---- main: per-anchor select2 + outputs ----
    int a = base + tid;
    size_t BA = (size_t)B * A;
    int nov = sNov;
    if (a < A) {
        size_t idx = bA + a;
        unsigned bits = rowbits0[idx];
        for (int j = 0; j < nov; j++)
            if (ovrA[j] == a) bits |= ovrBits[j];
        int pc = __popc(bits);
        int tgt, fg; float ov = 0.0f;
        float4 p = pdb[idx];
        if (pc > 1) {
            float bv = -1.0f; int bm = 0;
            for (int m = 0; m < M; m++) {
                float v = iou_pair(p, sg[m]);
                if (v > bv) { bv = v; bm = m; }
            }
            tgt = bm; fg = 1; ov = bv;
        } else if (pc == 1) {
            tgt = __ffs(bits) - 1; fg = 1;
            ov = iou_pair(p, sg[tgt]);
        } else { tgt = 0; fg = 0; }
        int lab = slab[tgt];
        int tl = min(max(lab, 0), C);            // clip(., 0, NUM_CLASSES)
        float norm = 0.0f;
        if (fg) {
            int li = (lab >= 0 && lab < C) ? lab : 0;
            float cls = pds[idx * (size_t)C + li];
            float ov6 = powf(ov, 6.0f);          // overlaps ** BETA
            float v = cls * ov6;                 // align_metric at (a, tgt)
            norm = v * ov / (v + 1e-9f);         // pam*pov/(pam+eps)
        }
        out[idx] = (float)tl;                                // tl
        ((float4*)(out + BA))[idx] = sg[tgt];                // tb
        out[BA * (size_t)(5 + C) + idx] = fg ? 1.0f : 0.0f;  // fg
        out[BA * (size_t)(6 + C) + idx] = (float)tgt;        // tgt
        snorm[tid] = norm;
        stl[tid] = tl;
    }
    __syncthreads();
    int cntA = min(256, A - base);
    int rowf4 = C >> 2;
    int nf4 = cntA * rowf4;
    float4* tsb = (float4*)(out + BA * 5 + (bA + base) * C);
    int q = 256 / rowf4, r = 256 - q * rowf4;
    int row = tid / rowf4;
    int c4  = tid - row * rowf4;
    for (int i = tid; i < nf4; i += 256) {
        float nv = snorm[row];
        int tl   = stl[row];
        int cb = c4 * 4;
        float4 v;
        v.x = (tl == cb + 0) ? nv : 0.0f;
        v.y = (tl == cb + 1) ? nv : 0.0f;
        v.z = (tl == cb + 2) ? nv : 0.0f;
        v.w = (tl == cb + 3) ? nv : 0.0f;
        tsb[i] = v;
        row += q; c4 += r;
        if (c4 >= rowf4) { c4 -= rowf4; row++; }
    }
}

extern "C" void kernel_launch(void* const* d_in, const int* in_sizes, int n_in,
                              void* d_out, int out_size, void* d_ws, size_t ws_size,
                              hipStream_t stream) {
    const float*  pd_scores = (const float*)d_in[0];
    const float4* pd_bboxes = (const float4*)d_in[1];
    const float2* anc       = (const float2*)d_in[2];
    const int*    gt_labels = (const int*)d_in[3];
    const float4* gt_bboxes = (const float4*)d_in[4];
    const void*   mask_gt   = d_in[5];

    int A = in_sizes[2] / 2;
    int B = in_sizes[1] / (A * 4);
    int M = in_sizes[3] / B;
    int C = (int)((long long)in_sizes[0] / ((long long)B * A));
    int nCh = (A + 255) / 256;
    int nw = (B * M) / 4; if (nw > 256) nw = 256;

    char* wp = (char*)d_ws;
    auto carve = [&](size_t bytes) -> char* {
        char* r = wp; wp += (bytes + 255) & ~(size_t)255; return r;
    };
    unsigned* rowbits0         = (unsigned*)carve((size_t)B * A * 4);
    short* tgt0                = (short*)carve((size_t)B * A * 2);
    unsigned long long* colKey = (unsigned long long*)carve((size_t)B * M * 8);
    unsigned char* needByte    = (unsigned char*)carve((size_t)B * M);
    int* cntChunk              = (int*)carve((size_t)B * nCh * 32 * 4);

    float* out = (float*)d_out;

    k_phase1<<<dim3(M + nCh, B), 256, 0, stream>>>(pd_bboxes, anc, gt_bboxes, mask_gt, nw,
                                                   colKey, needByte, rowbits0, tgt0,
                                                   cntChunk, A, M, nCh);
    k_final<<<dim3(nCh, B), 256, 0, stream>>>(pd_scores, pd_bboxes, gt_bboxes, gt_labels,
                                              mask_gt, nw, colKey, needByte, rowbits0,
                                              tgt0, cntChunk, out, A, M, C, B, nCh);
}